// Round 9
// baseline (194.969 us; speedup 1.0000x reference)
//
#include <hip/hip_runtime.h>

#define N_NODES 100000
#define N_EDGES 600000
#define D_FEAT  128
#define Q4      (N_EDGES / 4)     // 150000 int4 edge quads
#define BLOCKS  256
#define THREADS 256
#define P_SLICE 16                // slice copies (blocks per group)
#define G_GROUP 16                // node groups
#define RANGE   (N_NODES / G_GROUP)   // 6250 nodes per group, 25 KB LDS

// Atomic-free LDS-privatized scatter (R8 proved ~40us faster than global
// atomics). R8's post-timing failure attributed to ws overrun (14.4 MB);
// this version: slices stored fp16 -> TOTAL ws = 4.8 MB (< R7-proven 6.4 MB).
//   block b: g = b & 15 (node group), p = b >> 4 (record stripe set)
//   scan: LDS f32 tile over [g*RANGE,(g+1)*RANGE), flush fp16 to slice p
//   reduce: node n sums 16 fp16 slices (degree counts <= ~2048: exact in fp16)
// Math: S = D^-1/2(A+I)D^-1/2, z = x.W, out = S^2 z + b
//   dis = rsqrt(deg+1); y = dis*z
//   t1[c] = sum y[r];  w = dis^2*(t1+y)
//   t2[c] = sum w[r];  out = dis*(t2+w) + b

// ---- kA: projection z = x.W  +  fp16 degree slices ----
__global__ void __launch_bounds__(THREADS)
kA_proj_degscan(const float* __restrict__ x, const float* __restrict__ W,
                const int* __restrict__ col, float* __restrict__ z,
                _Float16* __restrict__ sl) {
    __shared__ float tile[RANGE];
    const int b = blockIdx.x, tid = threadIdx.x;
    const int g = b & (G_GROUP - 1), p = b >> 4;
    const int lo = g * RANGE;

    for (int i = tid; i < RANGE; i += THREADS) tile[i] = 0.0f;

    // projection: half-wave per node, 4-way ILP (2048 half-waves)
    {
        const int gtid = b * THREADS + tid;
        const int hw = gtid >> 5, hl = gtid & 31;
        float4 wv = ((const float4*)W)[hl];
        for (int n0 = hw; n0 < N_NODES / 4; n0 += 2048) {
            int n1 = n0 + N_NODES / 4, n2 = n0 + N_NODES / 2, n3 = n0 + 3 * (N_NODES / 4);
            float4 a0 = ((const float4*)(x + (size_t)n0 * D_FEAT))[hl];
            float4 a1 = ((const float4*)(x + (size_t)n1 * D_FEAT))[hl];
            float4 a2 = ((const float4*)(x + (size_t)n2 * D_FEAT))[hl];
            float4 a3 = ((const float4*)(x + (size_t)n3 * D_FEAT))[hl];
            float s0 = a0.x*wv.x + a0.y*wv.y + a0.z*wv.z + a0.w*wv.w;
            float s1 = a1.x*wv.x + a1.y*wv.y + a1.z*wv.z + a1.w*wv.w;
            float s2 = a2.x*wv.x + a2.y*wv.y + a2.z*wv.z + a2.w*wv.w;
            float s3 = a3.x*wv.x + a3.y*wv.y + a3.z*wv.z + a3.w*wv.w;
            #pragma unroll
            for (int off = 16; off > 0; off >>= 1) {
                s0 += __shfl_xor(s0, off, 32);
                s1 += __shfl_xor(s1, off, 32);
                s2 += __shfl_xor(s2, off, 32);
                s3 += __shfl_xor(s3, off, 32);
            }
            if (hl == 0) { z[n0] = s0; z[n1] = s1; z[n2] = s2; z[n3] = s3; }
        }
    }
    __syncthreads();

    for (int j = 0; ; ++j) {
        int q = (j * P_SLICE + p) * THREADS + tid;
        if (q >= Q4) break;
        int4 c = ((const int4*)col)[q];
        unsigned ux = (unsigned)(c.x - lo), uy = (unsigned)(c.y - lo);
        unsigned uz = (unsigned)(c.z - lo), uw = (unsigned)(c.w - lo);
        if (ux < RANGE) atomicAdd(&tile[ux], 1.0f);
        if (uy < RANGE) atomicAdd(&tile[uy], 1.0f);
        if (uz < RANGE) atomicAdd(&tile[uz], 1.0f);
        if (uw < RANGE) atomicAdd(&tile[uw], 1.0f);
    }
    __syncthreads();
    _Float16* base = sl + (size_t)p * N_NODES + lo;
    for (int i = tid; i < RANGE; i += THREADS) base[i] = (_Float16)tile[i];
}

// ---- generic float scan: tile[col-lo] += src[row], flush fp16 slice ----
__global__ void __launch_bounds__(THREADS)
kScanF(const int* __restrict__ row, const int* __restrict__ col,
       const float* __restrict__ src, _Float16* __restrict__ sl) {
    __shared__ float tile[RANGE];
    const int b = blockIdx.x, tid = threadIdx.x;
    const int g = b & (G_GROUP - 1), p = b >> 4;
    const int lo = g * RANGE;

    for (int i = tid; i < RANGE; i += THREADS) tile[i] = 0.0f;
    __syncthreads();

    for (int j = 0; ; ++j) {
        int q = (j * P_SLICE + p) * THREADS + tid;
        if (q >= Q4) break;
        int4 rr = ((const int4*)row)[q];
        int4 cc = ((const int4*)col)[q];
        unsigned ux = (unsigned)(cc.x - lo), uy = (unsigned)(cc.y - lo);
        unsigned uz = (unsigned)(cc.z - lo), uw = (unsigned)(cc.w - lo);
        if (ux < RANGE) atomicAdd(&tile[ux], src[rr.x]);
        if (uy < RANGE) atomicAdd(&tile[uy], src[rr.y]);
        if (uz < RANGE) atomicAdd(&tile[uz], src[rr.z]);
        if (uw < RANGE) atomicAdd(&tile[uw], src[rr.w]);
    }
    __syncthreads();
    _Float16* base = sl + (size_t)p * N_NODES + lo;
    for (int i = tid; i < RANGE; i += THREADS) base[i] = (_Float16)tile[i];
}

__device__ __forceinline__ float slice_sum(const _Float16* sl, int n) {
    float a = 0.0f;
    #pragma unroll
    for (int p = 0; p < P_SLICE; ++p) a += (float)sl[(size_t)p * N_NODES + n];
    return a;
}

// ---- kB: deg reduce -> dis, y = dis*z ----
__global__ void kB_degreduce(const _Float16* __restrict__ sl,
                             const float* __restrict__ z,
                             float* __restrict__ disA, float* __restrict__ yA) {
    int n = blockIdx.x * blockDim.x + threadIdx.x;
    if (n >= N_NODES) return;
    float dis = rsqrtf(slice_sum(sl, n) + 1.0f);   // +1 self loop (counts exact)
    disA[n] = dis;
    yA[n] = dis * z[n];
}

// ---- kD: t1 reduce -> w = dis^2*(t1+y) ----
__global__ void kD_t1reduce(const _Float16* __restrict__ sl,
                            const float* __restrict__ disA,
                            const float* __restrict__ yA,
                            float* __restrict__ wA) {
    int n = blockIdx.x * blockDim.x + threadIdx.x;
    if (n >= N_NODES) return;
    float dis = disA[n];
    wA[n] = dis * dis * (slice_sum(sl, n) + yA[n]);
}

// ---- kF: t2 reduce -> out = dis*(t2+w) + b ----
__global__ void kF_final(const _Float16* __restrict__ sl,
                         const float* __restrict__ disA,
                         const float* __restrict__ wA,
                         const float* __restrict__ b,
                         float* __restrict__ out) {
    int n = blockIdx.x * blockDim.x + threadIdx.x;
    if (n >= N_NODES) return;
    out[n] = disA[n] * (slice_sum(sl, n) + wA[n]) + b[0];
}

extern "C" void kernel_launch(void* const* d_in, const int* in_sizes, int n_in,
                              void* d_out, int out_size, void* d_ws, size_t ws_size,
                              hipStream_t stream) {
    const float* x  = (const float*)d_in[0];
    const int*   ei = (const int*)  d_in[1];   // [2,E] int32; row=ei[0:E], col=ei[E:2E]
    const float* W  = (const float*)d_in[2];
    const float* b  = (const float*)d_in[3];
    float* out = (float*)d_out;

    // ws: z | disA | yA | wA (4 x 400 KB) | slices fp16 (16*100000*2B = 3.2 MB)
    // total 4.8 MB  (< R7's proven-safe 6.4 MB footprint)
    float* z    = (float*)d_ws;
    float* disA = z    + N_NODES;
    float* yA   = disA + N_NODES;
    float* wA   = yA   + N_NODES;
    _Float16* sl = (_Float16*)(wA + N_NODES);

    const int* row = ei;
    const int* col = ei + N_EDGES;

    const int grid_node = (N_NODES + THREADS - 1) / THREADS;   // 391

    kA_proj_degscan<<<BLOCKS, THREADS, 0, stream>>>(x, W, col, z, sl);
    kB_degreduce   <<<grid_node, THREADS, 0, stream>>>(sl, z, disA, yA);
    kScanF         <<<BLOCKS, THREADS, 0, stream>>>(row, col, yA, sl);
    kD_t1reduce    <<<grid_node, THREADS, 0, stream>>>(sl, disA, yA, wA);
    kScanF         <<<BLOCKS, THREADS, 0, stream>>>(row, col, wA, sl);
    kF_final       <<<grid_node, THREADS, 0, stream>>>(sl, disA, wA, b, out);
}